// Round 5
// baseline (1402.798 us; speedup 1.0000x reference)
//
#include <hip/hip_runtime.h>
#include <hip/hip_bf16.h>
#include <cstdint>
#include <cstddef>

#define NA 50000
#define NP 100000
#define HH 256
#define LL 3
#define GP 25000            // NP/4 agg blocks
#define GA 12500            // NA/4 agg blocks

typedef __attribute__((ext_vector_type(8))) short short8;
typedef __attribute__((ext_vector_type(4))) float f32x4;

__device__ __forceinline__ float bf2f(unsigned int u16) {
    unsigned int x = u16 << 16;
    return __builtin_bit_cast(float, x);
}
__device__ __forceinline__ unsigned short f2bf(float f) {
    __hip_bfloat16 h = __float2bfloat16(f);
    return __builtin_bit_cast(unsigned short, h);
}

// ---------------- weight prep: WT[w][n*256+k] bf16, w = l*5 + t ----------------
// t0=Wl[l,0] (writes), t1=Wl[l,2] (cites), t2=Wr[l,0]+Wr[l,2] (P-root),
// t3=Wl[l,1] (rev), t4=Wr[l,1] (A-root)
__global__ void prep_w_k(const float* __restrict__ Wl, const float* __restrict__ Wr,
                         unsigned short* __restrict__ WT) {
    int gid = blockIdx.x * 256 + threadIdx.x;           // 15*65536 threads
    int w = gid >> 16;
    int within = gid & 65535;
    int n = within >> 8, k = within & 255;
    int l = w / 5, t = w % 5;
    float v;
    if (t == 0)      v = Wl[(size_t)((l * 3 + 0) * 256 + k) * 256 + n];
    else if (t == 1) v = Wl[(size_t)((l * 3 + 2) * 256 + k) * 256 + n];
    else if (t == 2) v = Wr[(size_t)((l * 3 + 0) * 256 + k) * 256 + n] +
                         Wr[(size_t)((l * 3 + 2) * 256 + k) * 256 + n];
    else if (t == 3) v = Wl[(size_t)((l * 3 + 1) * 256 + k) * 256 + n];
    else             v = Wr[(size_t)((l * 3 + 1) * 256 + k) * 256 + n];
    WT[(size_t)w * 65536 + n * 256 + k] = f2bf(v);
}

__global__ void prep_bias_k(const float* __restrict__ bl,
                            float* __restrict__ biasP, float* __restrict__ biasA) {
    int gid = blockIdx.x * 256 + threadIdx.x;           // 3*256 threads
    int l = gid >> 8, n = gid & 255;
    biasP[l * 256 + n] = bl[(l * 3 + 0) * 256 + n] + bl[(l * 3 + 2) * 256 + n];
    biasA[l * 256 + n] = bl[(l * 3 + 1) * 256 + n];
}

// ---------------- CSR build (fused over the 3 edge types) ----------------
__global__ void count3_k(const int* __restrict__ dw, const int* __restrict__ dc,
                         const int* __restrict__ dr, int* __restrict__ cnt,
                         int E, int egrid) {
    int b = blockIdx.x;
    int type = b / egrid, lb = b - type * egrid;
    int e = lb * 256 + threadIdx.x;
    if (e >= E) return;
    const int* d = (type == 0) ? dw : (type == 1) ? dc : dr;
    int base = (type == 0) ? 0 : (type == 1) ? NP : 2 * NP;
    atomicAdd(&cnt[base + d[e]], 1);
}

__global__ void scanA_k(const int* __restrict__ cnt, int* __restrict__ part,
                        int nbP, int nbA) {
    int b = blockIdx.x;
    int type, lb;
    if (b < nbP) { type = 0; lb = b; }
    else if (b < 2 * nbP) { type = 1; lb = b - nbP; }
    else { type = 2; lb = b - 2 * nbP; }
    int n = (type < 2) ? NP : NA;
    int base = (type == 0) ? 0 : (type == 1) ? NP : 2 * NP;
    __shared__ int sh[256];
    int i = lb * 256 + threadIdx.x;
    sh[threadIdx.x] = (i < n) ? cnt[base + i] : 0;
    __syncthreads();
    for (int s = 128; s > 0; s >>= 1) {
        if (threadIdx.x < s) sh[threadIdx.x] += sh[threadIdx.x + s];
        __syncthreads();
    }
    if (threadIdx.x == 0) part[type * 512 + lb] = sh[0];
}
__global__ void scanB_k(int* __restrict__ part, int nbP, int nbA) {
    int type = blockIdx.x;
    int nb = (type < 2) ? nbP : nbA;
    int* seg = part + type * 512;
    __shared__ int sh[512];
    int t = threadIdx.x;
    int v0 = (t < nb) ? seg[t] : 0;
    sh[t] = v0;
    __syncthreads();
    for (int off = 1; off < 512; off <<= 1) {
        int x = (t >= off) ? sh[t - off] : 0;
        __syncthreads();
        sh[t] += x;
        __syncthreads();
    }
    if (t < nb) seg[t] = sh[t] - v0;                    // exclusive
}
__global__ void scanC_k(const int* __restrict__ cnt, const int* __restrict__ part,
                        int* __restrict__ rp_w, int* __restrict__ rp_c,
                        int* __restrict__ rp_r, int nbP, int nbA) {
    int b = blockIdx.x;
    int type, lb;
    if (b < nbP) { type = 0; lb = b; }
    else if (b < 2 * nbP) { type = 1; lb = b - nbP; }
    else { type = 2; lb = b - 2 * nbP; }
    int n = (type < 2) ? NP : NA;
    int base = (type == 0) ? 0 : (type == 1) ? NP : 2 * NP;
    int* rowptr = (type == 0) ? rp_w : (type == 1) ? rp_c : rp_r;
    __shared__ int sh[256];
    int t = threadIdx.x;
    int i = lb * 256 + t;
    int v = (i < n) ? cnt[base + i] : 0;
    sh[t] = v;
    __syncthreads();
    for (int off = 1; off < 256; off <<= 1) {
        int x = (t >= off) ? sh[t - off] : 0;
        __syncthreads();
        if (t >= off) sh[t] += x;
        __syncthreads();
    }
    if (i < n) {
        int incl = sh[t];
        int pb = part[type * 512 + lb];
        rowptr[i] = pb + incl - v;
        if (i == n - 1) rowptr[n] = pb + incl;
    }
}
__global__ void fill3_k(const int* __restrict__ e_w, const int* __restrict__ e_c,
                        const int* __restrict__ e_r,
                        const int* __restrict__ rp_w, const int* __restrict__ rp_c,
                        const int* __restrict__ rp_r,
                        int* __restrict__ cursor,
                        int* __restrict__ col_w, int* __restrict__ col_c,
                        int* __restrict__ col_r, int E, int egrid) {
    int b = blockIdx.x;
    int type = b / egrid, lb = b - type * egrid;
    int e = lb * 256 + threadIdx.x;
    if (e >= E) return;
    const int* ep = (type == 0) ? e_w : (type == 1) ? e_c : e_r;
    const int* rowptr = (type == 0) ? rp_w : (type == 1) ? rp_c : rp_r;
    int* col = (type == 0) ? col_w : (type == 1) ? col_c : col_r;
    int base = (type == 0) ? 0 : (type == 1) ? NP : 2 * NP;
    int s = ep[e], d = ep[E + e];
    int pos = atomicAdd(&cursor[base + d], 1);
    col[rowptr[d] + pos] = s;
}

// ---------------- f32 -> bf16 cast (8 elems/thread) ----------------
__global__ void cast_bf16_k(const float* __restrict__ x, unsigned short* __restrict__ o, int n8) {
    int g = blockIdx.x * 256 + threadIdx.x;
    if (g >= n8) return;
    const float4* xp = reinterpret_cast<const float4*>(x) + (size_t)g * 2;
    float4 a = xp[0], b = xp[1];
    union { unsigned short u[8]; uint4 v; } r;
    r.u[0] = f2bf(a.x); r.u[1] = f2bf(a.y); r.u[2] = f2bf(a.z); r.u[3] = f2bf(a.w);
    r.u[4] = f2bf(b.x); r.u[5] = f2bf(b.y); r.u[6] = f2bf(b.z); r.u[7] = f2bf(b.w);
    reinterpret_cast<uint4*>(o)[g] = r.v;
}

// ---------------- fused CSR gather-mean: 3 jobs in one dispatch ----------------
__global__ void agg_fused_k(const unsigned short* __restrict__ xa,
                            const unsigned short* __restrict__ xp,
                            const int* __restrict__ rp_w, const int* __restrict__ col_w,
                            const int* __restrict__ rp_c, const int* __restrict__ col_c,
                            const int* __restrict__ rp_r, const int* __restrict__ col_r,
                            unsigned short* __restrict__ mW,
                            unsigned short* __restrict__ mC,
                            unsigned short* __restrict__ mR) {
    int b = blockIdx.x;
    const unsigned short* x; const int* rp; const int* cl; unsigned short* mn; int nd;
    if (b < GP)            { x = xa; rp = rp_w; cl = col_w; mn = mW; nd = NP; }
    else if (b < 2 * GP)   { b -= GP; x = xp; rp = rp_c; cl = col_c; mn = mC; nd = NP; }
    else                   { b -= 2 * GP; x = xp; rp = rp_r; cl = col_r; mn = mR; nd = NA; }
    int node = b * 4 + (threadIdx.x >> 6);
    if (node >= nd) return;
    int lane = threadIdx.x & 63;
    int half = lane >> 5, l32 = lane & 31;
    int beg = rp[node], end = rp[node + 1];
    float a0 = 0.f, a1 = 0.f, a2 = 0.f, a3 = 0.f, a4 = 0.f, a5 = 0.f, a6 = 0.f, a7 = 0.f;
    for (int j = beg + half; j < end; j += 2) {
        int s = cl[j];
        uint4 v = *reinterpret_cast<const uint4*>(x + (size_t)s * 256 + l32 * 8);
        a0 += bf2f(v.x & 0xffffu); a1 += bf2f(v.x >> 16);
        a2 += bf2f(v.y & 0xffffu); a3 += bf2f(v.y >> 16);
        a4 += bf2f(v.z & 0xffffu); a5 += bf2f(v.z >> 16);
        a6 += bf2f(v.w & 0xffffu); a7 += bf2f(v.w >> 16);
    }
    a0 += __shfl_xor(a0, 32); a1 += __shfl_xor(a1, 32);
    a2 += __shfl_xor(a2, 32); a3 += __shfl_xor(a3, 32);
    a4 += __shfl_xor(a4, 32); a5 += __shfl_xor(a5, 32);
    a6 += __shfl_xor(a6, 32); a7 += __shfl_xor(a7, 32);
    if (half == 0) {
        float sc = (end > beg) ? 1.0f / (float)(end - beg) : 0.f;
        uint4 r;
        r.x = (unsigned int)f2bf(a0 * sc) | ((unsigned int)f2bf(a1 * sc) << 16);
        r.y = (unsigned int)f2bf(a2 * sc) | ((unsigned int)f2bf(a3 * sc) << 16);
        r.z = (unsigned int)f2bf(a4 * sc) | ((unsigned int)f2bf(a5 * sc) << 16);
        r.w = (unsigned int)f2bf(a6 * sc) | ((unsigned int)f2bf(a7 * sc) << 16);
        *reinterpret_cast<uint4*>(mn + (size_t)node * 256 + l32 * 8) = r;
    }
}

// ---------------- fat fused GEMM v2: 128 rows x full 256 cols per block ----------------
// B staged in two sequential 64KB halves; A regs reused across halves.
// Epilogue staged through LDS for coalesced 16B/lane stores (no write-allocate RMW).
// grid: (mtP + mtA), block 512.
#define EP_STRIDE 132        // f32 row stride in epilogue LDS tile (bank-decorrelating pad)
template <bool LAST>
__global__ __launch_bounds__(512, 4)
void gemm_fat_k(const unsigned short* __restrict__ mW, const unsigned short* __restrict__ mC,
                const unsigned short* __restrict__ xp, const unsigned short* __restrict__ mR,
                const unsigned short* __restrict__ xa, const unsigned short* __restrict__ WT_l,
                const float* __restrict__ biasP, const float* __restrict__ biasA,
                void* __restrict__ outP, void* __restrict__ outA, int mtP) {
    __shared__ char lds[128 * EP_STRIDE * 4];           // 67584 B >= 65536 B for B-staging
    char* bsh = lds;
    float* eps = reinterpret_cast<float*>(lds);
    const int tid = threadIdx.x;

    const bool isP = (int)blockIdx.x < mtP;
    const int tile = isP ? blockIdx.x : blockIdx.x - mtP;
    const int parts = isP ? 3 : 2;
    const unsigned short* A0 = isP ? mW : mR;
    const unsigned short* A1 = isP ? mC : xa;
    const unsigned short* A2 = xp;
    const unsigned short* WTj = isP ? WT_l : WT_l + 3 * 65536;
    const float* bias = isP ? biasP : biasA;
    void* out = isP ? outP : outA;
    const int M = isP ? NP : NA;

    const int wid = tid >> 6;
    const int l = tid & 63;
    const int kgrp = (l >> 4) << 3;                     // 0,8,16,24
    int row = tile * 128 + (wid << 4) + (l & 15);
    int rowc = row < M ? row : M - 1;

    f32x4 acc[2][8];
    #pragma unroll
    for (int h = 0; h < 2; ++h)
        #pragma unroll
        for (int t = 0; t < 8; ++t) acc[h][t] = f32x4{0.f, 0.f, 0.f, 0.f};

    bool first = true;
    for (int p = 0; p < parts; ++p) {
        const unsigned short* Ap = (p == 0) ? A0 : (p == 1) ? A1 : A2;
        // A fragments once per part, reused for both N-halves
        uint4 a4[8];
        const unsigned short* Arow = Ap + (size_t)rowc * 256 + kgrp;
        #pragma unroll
        for (int s = 0; s < 8; ++s)
            a4[s] = *reinterpret_cast<const uint4*>(Arow + s * 32);

        #pragma unroll
        for (int h = 0; h < 2; ++h) {
            if (!first) __syncthreads();                // prior LDS reads done
            first = false;
            const unsigned short* Wt = WTj + (size_t)p * 65536 + h * (128 * 256);
            #pragma unroll
            for (int i = 0; i < 8; ++i) {               // stage 128 n-rows x 256 k, swizzled
                int byte = (i * 512 + tid) * 16;
                uint4 v = *reinterpret_cast<const uint4*>((const char*)Wt + byte);
                *reinterpret_cast<uint4*>(bsh + (byte ^ (((byte >> 9) & 7) << 4))) = v;
            }
            __syncthreads();
            #pragma unroll
            for (int s = 0; s < 8; ++s) {
                short8 a = __builtin_bit_cast(short8, a4[s]);
                #pragma unroll
                for (int t = 0; t < 8; ++t) {
                    int nl = (t << 4) + (l & 15);
                    int byte = (nl * 512 + s * 64 + kgrp * 2) ^ ((nl & 7) << 4);
                    short8 bfr = __builtin_bit_cast(short8, *reinterpret_cast<const uint4*>(bsh + byte));
                    acc[h][t] = __builtin_amdgcn_mfma_f32_16x16x32_bf16(a, bfr, acc[h][t], 0, 0, 0);
                }
            }
        }
    }

    // ---- epilogue via LDS: coalesced vector stores ----
    const int col = l & 15;
    const int rloc0 = (wid << 4) + ((l >> 4) << 2);     // local row base of this thread's quads
    #pragma unroll
    for (int h = 0; h < 2; ++h) {
        __syncthreads();                                // LDS (B or prev epilogue) reads done
        #pragma unroll
        for (int t = 0; t < 8; ++t) {
            int gc = (h << 7) + (t << 4) + col;
            float badd = bias[gc];
            #pragma unroll
            for (int j = 0; j < 4; ++j)
                eps[(rloc0 + j) * EP_STRIDE + (t << 4) + col] = acc[h][t][j] + badd;
        }
        __syncthreads();
        if (LAST) {
            // f32 out: 128 rows x 128 cols x 4B; 32 chunks/row, 8 per thread
            float* fout = reinterpret_cast<float*>(out);
            #pragma unroll
            for (int i = 0; i < 8; ++i) {
                int c = i * 512 + tid;
                int r = c >> 5, within = c & 31;
                int rg = tile * 128 + r;
                if (rg < M) {
                    const float* src = eps + r * EP_STRIDE + within * 4;
                    float4 v = *reinterpret_cast<const float4*>(src);
                    *reinterpret_cast<float4*>(fout + (size_t)rg * 256 + (h << 7) + within * 4) = v;
                }
            }
        } else {
            // bf16 out: 16 chunks/row, 4 per thread
            unsigned short* bout = reinterpret_cast<unsigned short*>(out);
            #pragma unroll
            for (int i = 0; i < 4; ++i) {
                int c = i * 512 + tid;
                int r = c >> 4, within = c & 15;
                int rg = tile * 128 + r;
                if (rg < M) {
                    const float* src = eps + r * EP_STRIDE + within * 8;
                    float4 lo = *reinterpret_cast<const float4*>(src);
                    float4 hi = *reinterpret_cast<const float4*>(src + 4);
                    uint4 v;
                    v.x = (unsigned int)f2bf(lo.x) | ((unsigned int)f2bf(lo.y) << 16);
                    v.y = (unsigned int)f2bf(lo.z) | ((unsigned int)f2bf(lo.w) << 16);
                    v.z = (unsigned int)f2bf(hi.x) | ((unsigned int)f2bf(hi.y) << 16);
                    v.w = (unsigned int)f2bf(hi.z) | ((unsigned int)f2bf(hi.w) << 16);
                    *reinterpret_cast<uint4*>(bout + (size_t)rg * 256 + (h << 7) + within * 8) = v;
                }
            }
        }
    }
}

extern "C" void kernel_launch(void* const* d_in, const int* in_sizes, int n_in,
                              void* d_out, int out_size, void* d_ws, size_t ws_size,
                              hipStream_t stream) {
    const float* x_author = (const float*)d_in[0];
    const float* x_paper  = (const float*)d_in[1];
    const int* e_w = (const int*)d_in[2];
    const int* e_r = (const int*)d_in[3];
    const int* e_c = (const int*)d_in[4];
    const float* Wl = (const float*)d_in[5];
    const float* bl = (const float*)d_in[6];
    const float* Wr = (const float*)d_in[7];
    const int E = in_sizes[2] / 2;

    float* outA = (float*)d_out;                         // [NA,256] f32
    float* outP = (float*)d_out + (size_t)NA * HH;       // [NP,256] f32

    size_t off = 0;
    auto carve = [&](size_t bytes) {
        void* p = (char*)d_ws + off;
        off += (bytes + 255) & ~(size_t)255;
        return p;
    };
    unsigned short* xa0   = (unsigned short*)carve((size_t)NA * HH * 2);
    unsigned short* xp0   = (unsigned short*)carve((size_t)NP * HH * 2);
    unsigned short* meanW = (unsigned short*)carve((size_t)NP * HH * 2);
    unsigned short* meanC = (unsigned short*)carve((size_t)NP * HH * 2);
    unsigned short* meanR = (unsigned short*)carve((size_t)NA * HH * 2);
    unsigned short* WT    = (unsigned short*)carve((size_t)15 * 65536 * 2);
    float* biasP = (float*)carve((size_t)LL * HH * 4);
    float* biasA = (float*)carve((size_t)LL * HH * 4);
    int* cnt    = (int*)carve((size_t)(2 * NP + NA) * 4);   // degree counts, reused as fill cursor
    int* rp_w   = (int*)carve((size_t)(NP + 1) * 4);
    int* rp_c   = (int*)carve((size_t)(NP + 1) * 4);
    int* rp_r   = (int*)carve((size_t)(NA + 1) * 4);
    int* part   = (int*)carve((size_t)2048 * 4);
    int* col_w  = (int*)carve((size_t)E * 4);
    int* col_c  = (int*)carve((size_t)E * 4);
    int* col_r  = (int*)carve((size_t)E * 4);
    (void)off; (void)ws_size; (void)n_in; (void)out_size;

    const size_t cntBytes = (size_t)(2 * NP + NA) * 4;
    const int egrid = (E + 255) / 256;
    const int nbP = (NP + 255) / 256, nbA = (NA + 255) / 256;
    const int mtP = (NP + 127) / 128, mtA = (NA + 127) / 128;

    // ---- one-time: weights, biases, CSR ----
    hipMemsetAsync(cnt, 0, cntBytes, stream);
    prep_w_k<<<3840, 256, 0, stream>>>(Wl, Wr, WT);
    prep_bias_k<<<3, 256, 0, stream>>>(bl, biasP, biasA);
    count3_k<<<3 * egrid, 256, 0, stream>>>(e_w + E, e_c + E, e_r + E, cnt, E, egrid);
    scanA_k<<<2 * nbP + nbA, 256, 0, stream>>>(cnt, part, nbP, nbA);
    scanB_k<<<3, 512, 0, stream>>>(part, nbP, nbA);
    scanC_k<<<2 * nbP + nbA, 256, 0, stream>>>(cnt, part, rp_w, rp_c, rp_r, nbP, nbA);
    hipMemsetAsync(cnt, 0, cntBytes, stream);            // re-zero -> fill cursor
    fill3_k<<<3 * egrid, 256, 0, stream>>>(e_w, e_c, e_r, rp_w, rp_c, rp_r,
                                           cnt, col_w, col_c, col_r, E, egrid);

    cast_bf16_k<<<(NA * HH / 8 + 255) / 256, 256, 0, stream>>>(x_author, xa0, NA * HH / 8);
    cast_bf16_k<<<(NP * HH / 8 + 255) / 256, 256, 0, stream>>>(x_paper, xp0, NP * HH / 8);

    // bf16 ping set inside d_out (overwritten by f32 at l=2)
    unsigned short* xa1 = (unsigned short*)d_out;
    unsigned short* xp1 = xa1 + (size_t)NA * HH;

    unsigned short* xa_cur = xa0; unsigned short* xp_cur = xp0;
    unsigned short* xa_nxt = xa1; unsigned short* xp_nxt = xp1;

    const int aggGrid = 2 * GP + GA;

    for (int l = 0; l < LL; ++l) {
        const unsigned short* WT_l = WT + (size_t)l * 5 * 65536;
        agg_fused_k<<<aggGrid, 256, 0, stream>>>(xa_cur, xp_cur, rp_w, col_w,
                                                 rp_c, col_c, rp_r, col_r,
                                                 meanW, meanC, meanR);
        if (l < LL - 1) {
            gemm_fat_k<false><<<mtP + mtA, 512, 0, stream>>>(
                meanW, meanC, xp_cur, meanR, xa_cur, WT_l,
                biasP + l * 256, biasA + l * 256, xp_nxt, xa_nxt, mtP);
            unsigned short* t;
            t = xa_cur; xa_cur = xa_nxt; xa_nxt = t;
            t = xp_cur; xp_cur = xp_nxt; xp_nxt = t;
        } else {
            gemm_fat_k<true><<<mtP + mtA, 512, 0, stream>>>(
                meanW, meanC, xp_cur, meanR, xa_cur, WT_l,
                biasP + l * 256, biasA + l * 256, outP, outA, mtP);
        }
    }
}

// Round 6
// 1137.617 us; speedup vs baseline: 1.2331x; 1.2331x over previous
//
#include <hip/hip_runtime.h>
#include <hip/hip_bf16.h>
#include <cstdint>
#include <cstddef>

#define NA 50000
#define NP 100000
#define HH 256
#define LL 3
#define GP 25000            // NP/4 agg blocks
#define GA 12500            // NA/4 agg blocks

typedef __attribute__((ext_vector_type(8))) short short8;
typedef __attribute__((ext_vector_type(4))) float f32x4;

__device__ __forceinline__ float bf2f(unsigned int u16) {
    unsigned int x = u16 << 16;
    return __builtin_bit_cast(float, x);
}
__device__ __forceinline__ unsigned short f2bf(float f) {
    __hip_bfloat16 h = __float2bfloat16(f);
    return __builtin_bit_cast(unsigned short, h);
}

// ---------------- weight prep: WT[w][n*256+k] bf16, w = l*5 + t ----------------
// t0=Wl[l,0] (writes), t1=Wl[l,2] (cites), t2=Wr[l,0]+Wr[l,2] (P-root),
// t3=Wl[l,1] (rev), t4=Wr[l,1] (A-root)
__global__ void prep_w_k(const float* __restrict__ Wl, const float* __restrict__ Wr,
                         unsigned short* __restrict__ WT) {
    int gid = blockIdx.x * 256 + threadIdx.x;           // 15*65536 threads
    int w = gid >> 16;
    int within = gid & 65535;
    int n = within >> 8, k = within & 255;
    int l = w / 5, t = w % 5;
    float v;
    if (t == 0)      v = Wl[(size_t)((l * 3 + 0) * 256 + k) * 256 + n];
    else if (t == 1) v = Wl[(size_t)((l * 3 + 2) * 256 + k) * 256 + n];
    else if (t == 2) v = Wr[(size_t)((l * 3 + 0) * 256 + k) * 256 + n] +
                         Wr[(size_t)((l * 3 + 2) * 256 + k) * 256 + n];
    else if (t == 3) v = Wl[(size_t)((l * 3 + 1) * 256 + k) * 256 + n];
    else             v = Wr[(size_t)((l * 3 + 1) * 256 + k) * 256 + n];
    WT[(size_t)w * 65536 + n * 256 + k] = f2bf(v);
}

__global__ void prep_bias_k(const float* __restrict__ bl,
                            float* __restrict__ biasP, float* __restrict__ biasA) {
    int gid = blockIdx.x * 256 + threadIdx.x;           // 3*256 threads
    int l = gid >> 8, n = gid & 255;
    biasP[l * 256 + n] = bl[(l * 3 + 0) * 256 + n] + bl[(l * 3 + 2) * 256 + n];
    biasA[l * 256 + n] = bl[(l * 3 + 1) * 256 + n];
}

// ---------------- CSR build (fused over the 3 edge types) ----------------
__global__ void count3_k(const int* __restrict__ dw, const int* __restrict__ dc,
                         const int* __restrict__ dr, int* __restrict__ cnt,
                         int E, int egrid) {
    int b = blockIdx.x;
    int type = b / egrid, lb = b - type * egrid;
    int e = lb * 256 + threadIdx.x;
    if (e >= E) return;
    const int* d = (type == 0) ? dw : (type == 1) ? dc : dr;
    int base = (type == 0) ? 0 : (type == 1) ? NP : 2 * NP;
    atomicAdd(&cnt[base + d[e]], 1);
}

__global__ void scanA_k(const int* __restrict__ cnt, int* __restrict__ part,
                        int nbP, int nbA) {
    int b = blockIdx.x;
    int type, lb;
    if (b < nbP) { type = 0; lb = b; }
    else if (b < 2 * nbP) { type = 1; lb = b - nbP; }
    else { type = 2; lb = b - 2 * nbP; }
    int n = (type < 2) ? NP : NA;
    int base = (type == 0) ? 0 : (type == 1) ? NP : 2 * NP;
    __shared__ int sh[256];
    int i = lb * 256 + threadIdx.x;
    sh[threadIdx.x] = (i < n) ? cnt[base + i] : 0;
    __syncthreads();
    for (int s = 128; s > 0; s >>= 1) {
        if (threadIdx.x < s) sh[threadIdx.x] += sh[threadIdx.x + s];
        __syncthreads();
    }
    if (threadIdx.x == 0) part[type * 512 + lb] = sh[0];
}
__global__ void scanB_k(int* __restrict__ part, int nbP, int nbA) {
    int type = blockIdx.x;
    int nb = (type < 2) ? nbP : nbA;
    int* seg = part + type * 512;
    __shared__ int sh[512];
    int t = threadIdx.x;
    int v0 = (t < nb) ? seg[t] : 0;
    sh[t] = v0;
    __syncthreads();
    for (int off = 1; off < 512; off <<= 1) {
        int x = (t >= off) ? sh[t - off] : 0;
        __syncthreads();
        sh[t] += x;
        __syncthreads();
    }
    if (t < nb) seg[t] = sh[t] - v0;                    // exclusive
}
__global__ void scanC_k(const int* __restrict__ cnt, const int* __restrict__ part,
                        int* __restrict__ rp_w, int* __restrict__ rp_c,
                        int* __restrict__ rp_r, int nbP, int nbA) {
    int b = blockIdx.x;
    int type, lb;
    if (b < nbP) { type = 0; lb = b; }
    else if (b < 2 * nbP) { type = 1; lb = b - nbP; }
    else { type = 2; lb = b - 2 * nbP; }
    int n = (type < 2) ? NP : NA;
    int base = (type == 0) ? 0 : (type == 1) ? NP : 2 * NP;
    int* rowptr = (type == 0) ? rp_w : (type == 1) ? rp_c : rp_r;
    __shared__ int sh[256];
    int t = threadIdx.x;
    int i = lb * 256 + t;
    int v = (i < n) ? cnt[base + i] : 0;
    sh[t] = v;
    __syncthreads();
    for (int off = 1; off < 256; off <<= 1) {
        int x = (t >= off) ? sh[t - off] : 0;
        __syncthreads();
        if (t >= off) sh[t] += x;
        __syncthreads();
    }
    if (i < n) {
        int incl = sh[t];
        int pb = part[type * 512 + lb];
        rowptr[i] = pb + incl - v;
        if (i == n - 1) rowptr[n] = pb + incl;
    }
}
__global__ void fill3_k(const int* __restrict__ e_w, const int* __restrict__ e_c,
                        const int* __restrict__ e_r,
                        const int* __restrict__ rp_w, const int* __restrict__ rp_c,
                        const int* __restrict__ rp_r,
                        int* __restrict__ cursor,
                        int* __restrict__ col_w, int* __restrict__ col_c,
                        int* __restrict__ col_r, int E, int egrid) {
    int b = blockIdx.x;
    int type = b / egrid, lb = b - type * egrid;
    int e = lb * 256 + threadIdx.x;
    if (e >= E) return;
    const int* ep = (type == 0) ? e_w : (type == 1) ? e_c : e_r;
    const int* rowptr = (type == 0) ? rp_w : (type == 1) ? rp_c : rp_r;
    int* col = (type == 0) ? col_w : (type == 1) ? col_c : col_r;
    int base = (type == 0) ? 0 : (type == 1) ? NP : 2 * NP;
    int s = ep[e], d = ep[E + e];
    int pos = atomicAdd(&cursor[base + d], 1);
    col[rowptr[d] + pos] = s;
}

// ---------------- f32 -> bf16 cast (8 elems/thread) ----------------
__global__ void cast_bf16_k(const float* __restrict__ x, unsigned short* __restrict__ o, int n8) {
    int g = blockIdx.x * 256 + threadIdx.x;
    if (g >= n8) return;
    const float4* xp = reinterpret_cast<const float4*>(x) + (size_t)g * 2;
    float4 a = xp[0], b = xp[1];
    union { unsigned short u[8]; uint4 v; } r;
    r.u[0] = f2bf(a.x); r.u[1] = f2bf(a.y); r.u[2] = f2bf(a.z); r.u[3] = f2bf(a.w);
    r.u[4] = f2bf(b.x); r.u[5] = f2bf(b.y); r.u[6] = f2bf(b.z); r.u[7] = f2bf(b.w);
    reinterpret_cast<uint4*>(o)[g] = r.v;
}

// ---------------- fused CSR gather-mean: 3 jobs in one dispatch ----------------
__global__ void agg_fused_k(const unsigned short* __restrict__ xa,
                            const unsigned short* __restrict__ xp,
                            const int* __restrict__ rp_w, const int* __restrict__ col_w,
                            const int* __restrict__ rp_c, const int* __restrict__ col_c,
                            const int* __restrict__ rp_r, const int* __restrict__ col_r,
                            unsigned short* __restrict__ mW,
                            unsigned short* __restrict__ mC,
                            unsigned short* __restrict__ mR) {
    int b = blockIdx.x;
    const unsigned short* x; const int* rp; const int* cl; unsigned short* mn; int nd;
    if (b < GP)            { x = xa; rp = rp_w; cl = col_w; mn = mW; nd = NP; }
    else if (b < 2 * GP)   { b -= GP; x = xp; rp = rp_c; cl = col_c; mn = mC; nd = NP; }
    else                   { b -= 2 * GP; x = xp; rp = rp_r; cl = col_r; mn = mR; nd = NA; }
    int node = b * 4 + (threadIdx.x >> 6);
    if (node >= nd) return;
    int lane = threadIdx.x & 63;
    int half = lane >> 5, l32 = lane & 31;
    int beg = rp[node], end = rp[node + 1];
    float a0 = 0.f, a1 = 0.f, a2 = 0.f, a3 = 0.f, a4 = 0.f, a5 = 0.f, a6 = 0.f, a7 = 0.f;
    for (int j = beg + half; j < end; j += 2) {
        int s = cl[j];
        uint4 v = *reinterpret_cast<const uint4*>(x + (size_t)s * 256 + l32 * 8);
        a0 += bf2f(v.x & 0xffffu); a1 += bf2f(v.x >> 16);
        a2 += bf2f(v.y & 0xffffu); a3 += bf2f(v.y >> 16);
        a4 += bf2f(v.z & 0xffffu); a5 += bf2f(v.z >> 16);
        a6 += bf2f(v.w & 0xffffu); a7 += bf2f(v.w >> 16);
    }
    a0 += __shfl_xor(a0, 32); a1 += __shfl_xor(a1, 32);
    a2 += __shfl_xor(a2, 32); a3 += __shfl_xor(a3, 32);
    a4 += __shfl_xor(a4, 32); a5 += __shfl_xor(a5, 32);
    a6 += __shfl_xor(a6, 32); a7 += __shfl_xor(a7, 32);
    if (half == 0) {
        float sc = (end > beg) ? 1.0f / (float)(end - beg) : 0.f;
        uint4 r;
        r.x = (unsigned int)f2bf(a0 * sc) | ((unsigned int)f2bf(a1 * sc) << 16);
        r.y = (unsigned int)f2bf(a2 * sc) | ((unsigned int)f2bf(a3 * sc) << 16);
        r.z = (unsigned int)f2bf(a4 * sc) | ((unsigned int)f2bf(a5 * sc) << 16);
        r.w = (unsigned int)f2bf(a6 * sc) | ((unsigned int)f2bf(a7 * sc) << 16);
        *reinterpret_cast<uint4*>(mn + (size_t)node * 256 + l32 * 8) = r;
    }
}

// ---------------- fat fused GEMM (R4 structure + LDS epilogue) ----------------
// grid (mtP+mtA, 2): 128-row tile, blockIdx.y = 128-col half. acc[8] only (no spill).
// Epilogue staged through LDS -> full-line vector stores (kills write-allocate RMW).
#define EP_STRIDE 132        // f32 row stride in epilogue LDS tile
template <bool LAST>
__global__ __launch_bounds__(512, 4)
void gemm_fat_k(const unsigned short* __restrict__ mW, const unsigned short* __restrict__ mC,
                const unsigned short* __restrict__ xp, const unsigned short* __restrict__ mR,
                const unsigned short* __restrict__ xa, const unsigned short* __restrict__ WT_l,
                const float* __restrict__ biasP, const float* __restrict__ biasA,
                void* __restrict__ outP, void* __restrict__ outA, int mtP) {
    __shared__ char lds[128 * EP_STRIDE * 4];           // 67584 B (>= 65536 B B-tile)
    char* bsh = lds;
    float* eps = reinterpret_cast<float*>(lds);
    const int tid = threadIdx.x;
    const int nhalf = blockIdx.y;

    const bool isP = (int)blockIdx.x < mtP;
    const int tile = isP ? blockIdx.x : blockIdx.x - mtP;
    const int parts = isP ? 3 : 2;
    const unsigned short* A0 = isP ? mW : mR;
    const unsigned short* A1 = isP ? mC : xa;
    const unsigned short* A2 = xp;
    const unsigned short* WTj = isP ? WT_l : WT_l + 3 * 65536;
    const float* bias = isP ? biasP : biasA;
    void* out = isP ? outP : outA;
    const int M = isP ? NP : NA;

    const int wid = tid >> 6;
    const int l = tid & 63;
    const int kgrp = (l >> 4) << 3;                     // 0,8,16,24
    int row = tile * 128 + (wid << 4) + (l & 15);
    int rowc = row < M ? row : M - 1;

    f32x4 acc[8];
    #pragma unroll
    for (int t = 0; t < 8; ++t) acc[t] = f32x4{0.f, 0.f, 0.f, 0.f};

    for (int p = 0; p < parts; ++p) {
        if (p) __syncthreads();
        const unsigned short* Ap = (p == 0) ? A0 : (p == 1) ? A1 : A2;
        // A-loads FIRST: latency hides under B staging + barrier
        uint4 a4[8];
        const unsigned short* Arow = Ap + (size_t)rowc * 256 + kgrp;
        #pragma unroll
        for (int s = 0; s < 8; ++s)
            a4[s] = *reinterpret_cast<const uint4*>(Arow + s * 32);
        // stage 128 n-rows x 256 k of B (this col-half), swizzled
        const unsigned short* Wt = WTj + (size_t)p * 65536 + nhalf * (128 * 256);
        #pragma unroll
        for (int i = 0; i < 8; ++i) {
            int byte = (i * 512 + tid) * 16;
            uint4 v = *reinterpret_cast<const uint4*>((const char*)Wt + byte);
            *reinterpret_cast<uint4*>(bsh + (byte ^ (((byte >> 9) & 7) << 4))) = v;
        }
        __syncthreads();

        #pragma unroll
        for (int s = 0; s < 8; ++s) {
            short8 a = __builtin_bit_cast(short8, a4[s]);
            #pragma unroll
            for (int t = 0; t < 8; ++t) {
                int nl = (t << 4) + (l & 15);
                int byte = (nl * 512 + s * 64 + kgrp * 2) ^ ((nl & 7) << 4);
                short8 bfr = __builtin_bit_cast(short8, *reinterpret_cast<const uint4*>(bsh + byte));
                acc[t] = __builtin_amdgcn_mfma_f32_16x16x32_bf16(a, bfr, acc[t], 0, 0, 0);
            }
        }
    }

    // ---- epilogue via LDS: coalesced full-line vector stores ----
    const int col = l & 15;
    const int rloc0 = (wid << 4) + ((l >> 4) << 2);     // local row base of this thread's quads
    __syncthreads();                                    // MFMA B-reads done; LDS now epilogue tile
    #pragma unroll
    for (int t = 0; t < 8; ++t) {
        int gc = (nhalf << 7) + (t << 4) + col;
        float badd = bias[gc];
        #pragma unroll
        for (int j = 0; j < 4; ++j)
            eps[(rloc0 + j) * EP_STRIDE + (t << 4) + col] = acc[t][j] + badd;
    }
    __syncthreads();
    if (LAST) {
        // f32 out: this half = 128 rows x 128 f32 (512 B/row); 32 float4 chunks/row, 8/thread
        float* fout = reinterpret_cast<float*>(out);
        #pragma unroll
        for (int i = 0; i < 8; ++i) {
            int c = i * 512 + tid;
            int r = c >> 5, within = c & 31;
            int rg = tile * 128 + r;
            if (rg < M) {
                const float* src = eps + r * EP_STRIDE + within * 4;
                float4 v = *reinterpret_cast<const float4*>(src);
                *reinterpret_cast<float4*>(fout + (size_t)rg * 256 + (nhalf << 7) + within * 4) = v;
            }
        }
    } else {
        // bf16 out: this half = 128 rows x 128 bf16 (256 B/row); 16 uint4 chunks/row, 4/thread
        unsigned short* bout = reinterpret_cast<unsigned short*>(out);
        #pragma unroll
        for (int i = 0; i < 4; ++i) {
            int c = i * 512 + tid;
            int r = c >> 4, within = c & 15;
            int rg = tile * 128 + r;
            if (rg < M) {
                const float* src = eps + r * EP_STRIDE + within * 8;
                float4 lo = *reinterpret_cast<const float4*>(src);
                float4 hi = *reinterpret_cast<const float4*>(src + 4);
                uint4 v;
                v.x = (unsigned int)f2bf(lo.x) | ((unsigned int)f2bf(lo.y) << 16);
                v.y = (unsigned int)f2bf(lo.z) | ((unsigned int)f2bf(lo.w) << 16);
                v.z = (unsigned int)f2bf(hi.x) | ((unsigned int)f2bf(hi.y) << 16);
                v.w = (unsigned int)f2bf(hi.z) | ((unsigned int)f2bf(hi.w) << 16);
                *reinterpret_cast<uint4*>(bout + (size_t)rg * 256 + (nhalf << 7) + within * 8) = v;
            }
        }
    }
}

extern "C" void kernel_launch(void* const* d_in, const int* in_sizes, int n_in,
                              void* d_out, int out_size, void* d_ws, size_t ws_size,
                              hipStream_t stream) {
    const float* x_author = (const float*)d_in[0];
    const float* x_paper  = (const float*)d_in[1];
    const int* e_w = (const int*)d_in[2];
    const int* e_r = (const int*)d_in[3];
    const int* e_c = (const int*)d_in[4];
    const float* Wl = (const float*)d_in[5];
    const float* bl = (const float*)d_in[6];
    const float* Wr = (const float*)d_in[7];
    const int E = in_sizes[2] / 2;

    float* outA = (float*)d_out;                         // [NA,256] f32
    float* outP = (float*)d_out + (size_t)NA * HH;       // [NP,256] f32

    size_t off = 0;
    auto carve = [&](size_t bytes) {
        void* p = (char*)d_ws + off;
        off += (bytes + 255) & ~(size_t)255;
        return p;
    };
    unsigned short* xa0   = (unsigned short*)carve((size_t)NA * HH * 2);
    unsigned short* xp0   = (unsigned short*)carve((size_t)NP * HH * 2);
    unsigned short* meanW = (unsigned short*)carve((size_t)NP * HH * 2);
    unsigned short* meanC = (unsigned short*)carve((size_t)NP * HH * 2);
    unsigned short* meanR = (unsigned short*)carve((size_t)NA * HH * 2);
    unsigned short* WT    = (unsigned short*)carve((size_t)15 * 65536 * 2);
    float* biasP = (float*)carve((size_t)LL * HH * 4);
    float* biasA = (float*)carve((size_t)LL * HH * 4);
    int* cnt    = (int*)carve((size_t)(2 * NP + NA) * 4);   // degree counts, reused as fill cursor
    int* rp_w   = (int*)carve((size_t)(NP + 1) * 4);
    int* rp_c   = (int*)carve((size_t)(NP + 1) * 4);
    int* rp_r   = (int*)carve((size_t)(NA + 1) * 4);
    int* part   = (int*)carve((size_t)2048 * 4);
    int* col_w  = (int*)carve((size_t)E * 4);
    int* col_c  = (int*)carve((size_t)E * 4);
    int* col_r  = (int*)carve((size_t)E * 4);
    (void)off; (void)ws_size; (void)n_in; (void)out_size;

    const size_t cntBytes = (size_t)(2 * NP + NA) * 4;
    const int egrid = (E + 255) / 256;
    const int nbP = (NP + 255) / 256, nbA = (NA + 255) / 256;
    const int mtP = (NP + 127) / 128, mtA = (NA + 127) / 128;

    // ---- one-time: weights, biases, CSR ----
    hipMemsetAsync(cnt, 0, cntBytes, stream);
    prep_w_k<<<3840, 256, 0, stream>>>(Wl, Wr, WT);
    prep_bias_k<<<3, 256, 0, stream>>>(bl, biasP, biasA);
    count3_k<<<3 * egrid, 256, 0, stream>>>(e_w + E, e_c + E, e_r + E, cnt, E, egrid);
    scanA_k<<<2 * nbP + nbA, 256, 0, stream>>>(cnt, part, nbP, nbA);
    scanB_k<<<3, 512, 0, stream>>>(part, nbP, nbA);
    scanC_k<<<2 * nbP + nbA, 256, 0, stream>>>(cnt, part, rp_w, rp_c, rp_r, nbP, nbA);
    hipMemsetAsync(cnt, 0, cntBytes, stream);            // re-zero -> fill cursor
    fill3_k<<<3 * egrid, 256, 0, stream>>>(e_w, e_c, e_r, rp_w, rp_c, rp_r,
                                           cnt, col_w, col_c, col_r, E, egrid);

    cast_bf16_k<<<(NA * HH / 8 + 255) / 256, 256, 0, stream>>>(x_author, xa0, NA * HH / 8);
    cast_bf16_k<<<(NP * HH / 8 + 255) / 256, 256, 0, stream>>>(x_paper, xp0, NP * HH / 8);

    // bf16 ping set inside d_out (overwritten by f32 at l=2)
    unsigned short* xa1 = (unsigned short*)d_out;
    unsigned short* xp1 = xa1 + (size_t)NA * HH;

    unsigned short* xa_cur = xa0; unsigned short* xp_cur = xp0;
    unsigned short* xa_nxt = xa1; unsigned short* xp_nxt = xp1;

    const int aggGrid = 2 * GP + GA;

    for (int l = 0; l < LL; ++l) {
        const unsigned short* WT_l = WT + (size_t)l * 5 * 65536;
        agg_fused_k<<<aggGrid, 256, 0, stream>>>(xa_cur, xp_cur, rp_w, col_w,
                                                 rp_c, col_c, rp_r, col_r,
                                                 meanW, meanC, meanR);
        if (l < LL - 1) {
            gemm_fat_k<false><<<dim3(mtP + mtA, 2), 512, 0, stream>>>(
                meanW, meanC, xp_cur, meanR, xa_cur, WT_l,
                biasP + l * 256, biasA + l * 256, xp_nxt, xa_nxt, mtP);
            unsigned short* t;
            t = xa_cur; xa_cur = xa_nxt; xa_nxt = t;
            t = xp_cur; xp_cur = xp_nxt; xp_nxt = t;
        } else {
            gemm_fat_k<true><<<dim3(mtP + mtA, 2), 512, 0, stream>>>(
                meanW, meanC, xp_cur, meanR, xa_cur, WT_l,
                biasP + l * 256, biasA + l * 256, outP, outA, mtP);
        }
    }
}

// Round 7
// 966.760 us; speedup vs baseline: 1.4510x; 1.1767x over previous
//
#include <hip/hip_runtime.h>
#include <hip/hip_bf16.h>
#include <cstdint>
#include <cstddef>

#define NA 50000
#define NP 100000
#define HH 256
#define LL 3
#define GP 25000            // NP/4 agg blocks
#define GA 12500            // NA/4 agg blocks

typedef __attribute__((ext_vector_type(8))) short short8;
typedef __attribute__((ext_vector_type(4))) float f32x4;

__device__ __forceinline__ float bf2f(unsigned int u16) {
    unsigned int x = u16 << 16;
    return __builtin_bit_cast(float, x);
}
__device__ __forceinline__ unsigned short f2bf(float f) {
    __hip_bfloat16 h = __float2bfloat16(f);
    return __builtin_bit_cast(unsigned short, h);
}

// ---------------- weight prep: WT[w][n*256+k] bf16, w = l*5 + t ----------------
// t0=Wl[l,0] (writes), t1=Wl[l,2] (cites), t2=Wr[l,0]+Wr[l,2] (P-root),
// t3=Wl[l,1] (rev), t4=Wr[l,1] (A-root)
__global__ void prep_w_k(const float* __restrict__ Wl, const float* __restrict__ Wr,
                         unsigned short* __restrict__ WT) {
    int gid = blockIdx.x * 256 + threadIdx.x;           // 15*65536 threads
    int w = gid >> 16;
    int within = gid & 65535;
    int n = within >> 8, k = within & 255;
    int l = w / 5, t = w % 5;
    float v;
    if (t == 0)      v = Wl[(size_t)((l * 3 + 0) * 256 + k) * 256 + n];
    else if (t == 1) v = Wl[(size_t)((l * 3 + 2) * 256 + k) * 256 + n];
    else if (t == 2) v = Wr[(size_t)((l * 3 + 0) * 256 + k) * 256 + n] +
                         Wr[(size_t)((l * 3 + 2) * 256 + k) * 256 + n];
    else if (t == 3) v = Wl[(size_t)((l * 3 + 1) * 256 + k) * 256 + n];
    else             v = Wr[(size_t)((l * 3 + 1) * 256 + k) * 256 + n];
    WT[(size_t)w * 65536 + n * 256 + k] = f2bf(v);
}

__global__ void prep_bias_k(const float* __restrict__ bl,
                            float* __restrict__ biasP, float* __restrict__ biasA) {
    int gid = blockIdx.x * 256 + threadIdx.x;           // 3*256 threads
    int l = gid >> 8, n = gid & 255;
    biasP[l * 256 + n] = bl[(l * 3 + 0) * 256 + n] + bl[(l * 3 + 2) * 256 + n];
    biasA[l * 256 + n] = bl[(l * 3 + 1) * 256 + n];
}

// ---------------- CSR build (fused over the 3 edge types) ----------------
__global__ void count3_k(const int* __restrict__ dw, const int* __restrict__ dc,
                         const int* __restrict__ dr, int* __restrict__ cnt,
                         int E, int egrid) {
    int b = blockIdx.x;
    int type = b / egrid, lb = b - type * egrid;
    int e = lb * 256 + threadIdx.x;
    if (e >= E) return;
    const int* d = (type == 0) ? dw : (type == 1) ? dc : dr;
    int base = (type == 0) ? 0 : (type == 1) ? NP : 2 * NP;
    atomicAdd(&cnt[base + d[e]], 1);
}

__global__ void scanA_k(const int* __restrict__ cnt, int* __restrict__ part,
                        int nbP, int nbA) {
    int b = blockIdx.x;
    int type, lb;
    if (b < nbP) { type = 0; lb = b; }
    else if (b < 2 * nbP) { type = 1; lb = b - nbP; }
    else { type = 2; lb = b - 2 * nbP; }
    int n = (type < 2) ? NP : NA;
    int base = (type == 0) ? 0 : (type == 1) ? NP : 2 * NP;
    __shared__ int sh[256];
    int i = lb * 256 + threadIdx.x;
    sh[threadIdx.x] = (i < n) ? cnt[base + i] : 0;
    __syncthreads();
    for (int s = 128; s > 0; s >>= 1) {
        if (threadIdx.x < s) sh[threadIdx.x] += sh[threadIdx.x + s];
        __syncthreads();
    }
    if (threadIdx.x == 0) part[type * 512 + lb] = sh[0];
}
__global__ void scanB_k(int* __restrict__ part, int nbP, int nbA) {
    int type = blockIdx.x;
    int nb = (type < 2) ? nbP : nbA;
    int* seg = part + type * 512;
    __shared__ int sh[512];
    int t = threadIdx.x;
    int v0 = (t < nb) ? seg[t] : 0;
    sh[t] = v0;
    __syncthreads();
    for (int off = 1; off < 512; off <<= 1) {
        int x = (t >= off) ? sh[t - off] : 0;
        __syncthreads();
        sh[t] += x;
        __syncthreads();
    }
    if (t < nb) seg[t] = sh[t] - v0;                    // exclusive
}
__global__ void scanC_k(const int* __restrict__ cnt, const int* __restrict__ part,
                        int* __restrict__ rp_w, int* __restrict__ rp_c,
                        int* __restrict__ rp_r, int nbP, int nbA) {
    int b = blockIdx.x;
    int type, lb;
    if (b < nbP) { type = 0; lb = b; }
    else if (b < 2 * nbP) { type = 1; lb = b - nbP; }
    else { type = 2; lb = b - 2 * nbP; }
    int n = (type < 2) ? NP : NA;
    int base = (type == 0) ? 0 : (type == 1) ? NP : 2 * NP;
    int* rowptr = (type == 0) ? rp_w : (type == 1) ? rp_c : rp_r;
    __shared__ int sh[256];
    int t = threadIdx.x;
    int i = lb * 256 + t;
    int v = (i < n) ? cnt[base + i] : 0;
    sh[t] = v;
    __syncthreads();
    for (int off = 1; off < 256; off <<= 1) {
        int x = (t >= off) ? sh[t - off] : 0;
        __syncthreads();
        if (t >= off) sh[t] += x;
        __syncthreads();
    }
    if (i < n) {
        int incl = sh[t];
        int pb = part[type * 512 + lb];
        rowptr[i] = pb + incl - v;
        if (i == n - 1) rowptr[n] = pb + incl;
    }
}
__global__ void fill3_k(const int* __restrict__ e_w, const int* __restrict__ e_c,
                        const int* __restrict__ e_r,
                        const int* __restrict__ rp_w, const int* __restrict__ rp_c,
                        const int* __restrict__ rp_r,
                        int* __restrict__ cursor,
                        int* __restrict__ col_w, int* __restrict__ col_c,
                        int* __restrict__ col_r, int E, int egrid) {
    int b = blockIdx.x;
    int type = b / egrid, lb = b - type * egrid;
    int e = lb * 256 + threadIdx.x;
    if (e >= E) return;
    const int* ep = (type == 0) ? e_w : (type == 1) ? e_c : e_r;
    const int* rowptr = (type == 0) ? rp_w : (type == 1) ? rp_c : rp_r;
    int* col = (type == 0) ? col_w : (type == 1) ? col_c : col_r;
    int base = (type == 0) ? 0 : (type == 1) ? NP : 2 * NP;
    int s = ep[e], d = ep[E + e];
    int pos = atomicAdd(&cursor[base + d], 1);
    col[rowptr[d] + pos] = s;
}

// ---------------- f32 -> bf16 cast (8 elems/thread) ----------------
__global__ void cast_bf16_k(const float* __restrict__ x, unsigned short* __restrict__ o, int n8) {
    int g = blockIdx.x * 256 + threadIdx.x;
    if (g >= n8) return;
    const float4* xp = reinterpret_cast<const float4*>(x) + (size_t)g * 2;
    float4 a = xp[0], b = xp[1];
    union { unsigned short u[8]; uint4 v; } r;
    r.u[0] = f2bf(a.x); r.u[1] = f2bf(a.y); r.u[2] = f2bf(a.z); r.u[3] = f2bf(a.w);
    r.u[4] = f2bf(b.x); r.u[5] = f2bf(b.y); r.u[6] = f2bf(b.z); r.u[7] = f2bf(b.w);
    reinterpret_cast<uint4*>(o)[g] = r.v;
}

// ---------------- fused CSR gather-mean: 3 jobs in one dispatch ----------------
__global__ void agg_fused_k(const unsigned short* __restrict__ xa,
                            const unsigned short* __restrict__ xp,
                            const int* __restrict__ rp_w, const int* __restrict__ col_w,
                            const int* __restrict__ rp_c, const int* __restrict__ col_c,
                            const int* __restrict__ rp_r, const int* __restrict__ col_r,
                            unsigned short* __restrict__ mW,
                            unsigned short* __restrict__ mC,
                            unsigned short* __restrict__ mR) {
    int b = blockIdx.x;
    const unsigned short* x; const int* rp; const int* cl; unsigned short* mn; int nd;
    if (b < GP)            { x = xa; rp = rp_w; cl = col_w; mn = mW; nd = NP; }
    else if (b < 2 * GP)   { b -= GP; x = xp; rp = rp_c; cl = col_c; mn = mC; nd = NP; }
    else                   { b -= 2 * GP; x = xp; rp = rp_r; cl = col_r; mn = mR; nd = NA; }
    int node = b * 4 + (threadIdx.x >> 6);
    if (node >= nd) return;
    int lane = threadIdx.x & 63;
    int half = lane >> 5, l32 = lane & 31;
    int beg = rp[node], end = rp[node + 1];
    float a0 = 0.f, a1 = 0.f, a2 = 0.f, a3 = 0.f, a4 = 0.f, a5 = 0.f, a6 = 0.f, a7 = 0.f;
    for (int j = beg + half; j < end; j += 2) {
        int s = cl[j];
        uint4 v = *reinterpret_cast<const uint4*>(x + (size_t)s * 256 + l32 * 8);
        a0 += bf2f(v.x & 0xffffu); a1 += bf2f(v.x >> 16);
        a2 += bf2f(v.y & 0xffffu); a3 += bf2f(v.y >> 16);
        a4 += bf2f(v.z & 0xffffu); a5 += bf2f(v.z >> 16);
        a6 += bf2f(v.w & 0xffffu); a7 += bf2f(v.w >> 16);
    }
    a0 += __shfl_xor(a0, 32); a1 += __shfl_xor(a1, 32);
    a2 += __shfl_xor(a2, 32); a3 += __shfl_xor(a3, 32);
    a4 += __shfl_xor(a4, 32); a5 += __shfl_xor(a5, 32);
    a6 += __shfl_xor(a6, 32); a7 += __shfl_xor(a7, 32);
    if (half == 0) {
        float sc = (end > beg) ? 1.0f / (float)(end - beg) : 0.f;
        uint4 r;
        r.x = (unsigned int)f2bf(a0 * sc) | ((unsigned int)f2bf(a1 * sc) << 16);
        r.y = (unsigned int)f2bf(a2 * sc) | ((unsigned int)f2bf(a3 * sc) << 16);
        r.z = (unsigned int)f2bf(a4 * sc) | ((unsigned int)f2bf(a5 * sc) << 16);
        r.w = (unsigned int)f2bf(a6 * sc) | ((unsigned int)f2bf(a7 * sc) << 16);
        *reinterpret_cast<uint4*>(mn + (size_t)node * 256 + l32 * 8) = r;
    }
}

// ---------------- fat fused GEMM: 128 rows x full 256 cols, reg-capped at 128 ----------------
// B staged in two sequential 64KB halves; A fragments loaded once, reused for both halves.
// Epilogue staged through LDS -> full-line vector stores. __launch_bounds__(512,2):
// VGPR cap 128 (acc[2][8]=64 + a4[8]=32 + working fits; NO spill). LDS caps at 2 blocks/CU anyway.
#define EP_STRIDE 132        // f32 row stride in epilogue LDS tile
template <bool LAST>
__global__ __launch_bounds__(512, 2)
void gemm_fat_k(const unsigned short* __restrict__ mW, const unsigned short* __restrict__ mC,
                const unsigned short* __restrict__ xp, const unsigned short* __restrict__ mR,
                const unsigned short* __restrict__ xa, const unsigned short* __restrict__ WT_l,
                const float* __restrict__ biasP, const float* __restrict__ biasA,
                void* __restrict__ outP, void* __restrict__ outA, int mtP) {
    __shared__ char lds[128 * EP_STRIDE * 4];           // 67584 B >= 65536 B for B-staging
    char* bsh = lds;
    float* eps = reinterpret_cast<float*>(lds);
    const int tid = threadIdx.x;

    const bool isP = (int)blockIdx.x < mtP;
    const int tile = isP ? blockIdx.x : blockIdx.x - mtP;
    const int parts = isP ? 3 : 2;
    const unsigned short* A0 = isP ? mW : mR;
    const unsigned short* A1 = isP ? mC : xa;
    const unsigned short* A2 = xp;
    const unsigned short* WTj = isP ? WT_l : WT_l + 3 * 65536;
    const float* bias = isP ? biasP : biasA;
    void* out = isP ? outP : outA;
    const int M = isP ? NP : NA;

    const int wid = tid >> 6;
    const int l = tid & 63;
    const int kgrp = (l >> 4) << 3;                     // 0,8,16,24
    int row = tile * 128 + (wid << 4) + (l & 15);
    int rowc = row < M ? row : M - 1;

    f32x4 acc[2][8];
    #pragma unroll
    for (int h = 0; h < 2; ++h)
        #pragma unroll
        for (int t = 0; t < 8; ++t) acc[h][t] = f32x4{0.f, 0.f, 0.f, 0.f};

    bool first = true;
    for (int p = 0; p < parts; ++p) {
        const unsigned short* Ap = (p == 0) ? A0 : (p == 1) ? A1 : A2;
        // A fragments once per part, reused for both N-halves
        uint4 a4[8];
        const unsigned short* Arow = Ap + (size_t)rowc * 256 + kgrp;
        #pragma unroll
        for (int s = 0; s < 8; ++s)
            a4[s] = *reinterpret_cast<const uint4*>(Arow + s * 32);

        #pragma unroll
        for (int h = 0; h < 2; ++h) {
            if (!first) __syncthreads();                // prior LDS reads done
            first = false;
            const unsigned short* Wt = WTj + (size_t)p * 65536 + h * (128 * 256);
            #pragma unroll
            for (int i = 0; i < 8; ++i) {               // stage 128 n-rows x 256 k, swizzled
                int byte = (i * 512 + tid) * 16;
                uint4 v = *reinterpret_cast<const uint4*>((const char*)Wt + byte);
                *reinterpret_cast<uint4*>(bsh + (byte ^ (((byte >> 9) & 7) << 4))) = v;
            }
            __syncthreads();
            #pragma unroll
            for (int s = 0; s < 8; ++s) {
                short8 a = __builtin_bit_cast(short8, a4[s]);
                #pragma unroll
                for (int t = 0; t < 8; ++t) {
                    int nl = (t << 4) + (l & 15);
                    int byte = (nl * 512 + s * 64 + kgrp * 2) ^ ((nl & 7) << 4);
                    short8 bfr = __builtin_bit_cast(short8, *reinterpret_cast<const uint4*>(bsh + byte));
                    acc[h][t] = __builtin_amdgcn_mfma_f32_16x16x32_bf16(a, bfr, acc[h][t], 0, 0, 0);
                }
            }
        }
    }

    // ---- epilogue via LDS: coalesced full-line vector stores ----
    const int col = l & 15;
    const int rloc0 = (wid << 4) + ((l >> 4) << 2);     // local row base of this thread's quads
    #pragma unroll
    for (int h = 0; h < 2; ++h) {
        __syncthreads();                                // LDS (B or prev epilogue) reads done
        #pragma unroll
        for (int t = 0; t < 8; ++t) {
            int gc = (h << 7) + (t << 4) + col;
            float badd = bias[gc];
            #pragma unroll
            for (int j = 0; j < 4; ++j)
                eps[(rloc0 + j) * EP_STRIDE + (t << 4) + col] = acc[h][t][j] + badd;
        }
        __syncthreads();
        if (LAST) {
            // f32 out: 128 rows x 128 cols x 4B; 32 float4 chunks/row, 8 per thread
            float* fout = reinterpret_cast<float*>(out);
            #pragma unroll
            for (int i = 0; i < 8; ++i) {
                int c = i * 512 + tid;
                int r = c >> 5, within = c & 31;
                int rg = tile * 128 + r;
                if (rg < M) {
                    const float* src = eps + r * EP_STRIDE + within * 4;
                    float4 v = *reinterpret_cast<const float4*>(src);
                    *reinterpret_cast<float4*>(fout + (size_t)rg * 256 + (h << 7) + within * 4) = v;
                }
            }
        } else {
            // bf16 out: 16 uint4 chunks/row, 4 per thread
            unsigned short* bout = reinterpret_cast<unsigned short*>(out);
            #pragma unroll
            for (int i = 0; i < 4; ++i) {
                int c = i * 512 + tid;
                int r = c >> 4, within = c & 15;
                int rg = tile * 128 + r;
                if (rg < M) {
                    const float* src = eps + r * EP_STRIDE + within * 8;
                    float4 lo = *reinterpret_cast<const float4*>(src);
                    float4 hi = *reinterpret_cast<const float4*>(src + 4);
                    uint4 v;
                    v.x = (unsigned int)f2bf(lo.x) | ((unsigned int)f2bf(lo.y) << 16);
                    v.y = (unsigned int)f2bf(lo.z) | ((unsigned int)f2bf(lo.w) << 16);
                    v.z = (unsigned int)f2bf(hi.x) | ((unsigned int)f2bf(hi.y) << 16);
                    v.w = (unsigned int)f2bf(hi.z) | ((unsigned int)f2bf(hi.w) << 16);
                    *reinterpret_cast<uint4*>(bout + (size_t)rg * 256 + (h << 7) + within * 8) = v;
                }
            }
        }
    }
}

extern "C" void kernel_launch(void* const* d_in, const int* in_sizes, int n_in,
                              void* d_out, int out_size, void* d_ws, size_t ws_size,
                              hipStream_t stream) {
    const float* x_author = (const float*)d_in[0];
    const float* x_paper  = (const float*)d_in[1];
    const int* e_w = (const int*)d_in[2];
    const int* e_r = (const int*)d_in[3];
    const int* e_c = (const int*)d_in[4];
    const float* Wl = (const float*)d_in[5];
    const float* bl = (const float*)d_in[6];
    const float* Wr = (const float*)d_in[7];
    const int E = in_sizes[2] / 2;

    float* outA = (float*)d_out;                         // [NA,256] f32
    float* outP = (float*)d_out + (size_t)NA * HH;       // [NP,256] f32

    size_t off = 0;
    auto carve = [&](size_t bytes) {
        void* p = (char*)d_ws + off;
        off += (bytes + 255) & ~(size_t)255;
        return p;
    };
    unsigned short* xa0   = (unsigned short*)carve((size_t)NA * HH * 2);
    unsigned short* xp0   = (unsigned short*)carve((size_t)NP * HH * 2);
    unsigned short* meanW = (unsigned short*)carve((size_t)NP * HH * 2);
    unsigned short* meanC = (unsigned short*)carve((size_t)NP * HH * 2);
    unsigned short* meanR = (unsigned short*)carve((size_t)NA * HH * 2);
    unsigned short* WT    = (unsigned short*)carve((size_t)15 * 65536 * 2);
    float* biasP = (float*)carve((size_t)LL * HH * 4);
    float* biasA = (float*)carve((size_t)LL * HH * 4);
    int* cnt    = (int*)carve((size_t)(2 * NP + NA) * 4);   // degree counts, reused as fill cursor
    int* rp_w   = (int*)carve((size_t)(NP + 1) * 4);
    int* rp_c   = (int*)carve((size_t)(NP + 1) * 4);
    int* rp_r   = (int*)carve((size_t)(NA + 1) * 4);
    int* part   = (int*)carve((size_t)2048 * 4);
    int* col_w  = (int*)carve((size_t)E * 4);
    int* col_c  = (int*)carve((size_t)E * 4);
    int* col_r  = (int*)carve((size_t)E * 4);
    (void)off; (void)ws_size; (void)n_in; (void)out_size;

    const size_t cntBytes = (size_t)(2 * NP + NA) * 4;
    const int egrid = (E + 255) / 256;
    const int nbP = (NP + 255) / 256, nbA = (NA + 255) / 256;
    const int mtP = (NP + 127) / 128, mtA = (NA + 127) / 128;

    // ---- one-time: weights, biases, CSR ----
    hipMemsetAsync(cnt, 0, cntBytes, stream);
    prep_w_k<<<3840, 256, 0, stream>>>(Wl, Wr, WT);
    prep_bias_k<<<3, 256, 0, stream>>>(bl, biasP, biasA);
    count3_k<<<3 * egrid, 256, 0, stream>>>(e_w + E, e_c + E, e_r + E, cnt, E, egrid);
    scanA_k<<<2 * nbP + nbA, 256, 0, stream>>>(cnt, part, nbP, nbA);
    scanB_k<<<3, 512, 0, stream>>>(part, nbP, nbA);
    scanC_k<<<2 * nbP + nbA, 256, 0, stream>>>(cnt, part, rp_w, rp_c, rp_r, nbP, nbA);
    hipMemsetAsync(cnt, 0, cntBytes, stream);            // re-zero -> fill cursor
    fill3_k<<<3 * egrid, 256, 0, stream>>>(e_w, e_c, e_r, rp_w, rp_c, rp_r,
                                           cnt, col_w, col_c, col_r, E, egrid);

    cast_bf16_k<<<(NA * HH / 8 + 255) / 256, 256, 0, stream>>>(x_author, xa0, NA * HH / 8);
    cast_bf16_k<<<(NP * HH / 8 + 255) / 256, 256, 0, stream>>>(x_paper, xp0, NP * HH / 8);

    // bf16 ping set inside d_out (overwritten by f32 at l=2)
    unsigned short* xa1 = (unsigned short*)d_out;
    unsigned short* xp1 = xa1 + (size_t)NA * HH;

    unsigned short* xa_cur = xa0; unsigned short* xp_cur = xp0;
    unsigned short* xa_nxt = xa1; unsigned short* xp_nxt = xp1;

    const int aggGrid = 2 * GP + GA;

    for (int l = 0; l < LL; ++l) {
        const unsigned short* WT_l = WT + (size_t)l * 5 * 65536;
        agg_fused_k<<<aggGrid, 256, 0, stream>>>(xa_cur, xp_cur, rp_w, col_w,
                                                 rp_c, col_c, rp_r, col_r,
                                                 meanW, meanC, meanR);
        if (l < LL - 1) {
            gemm_fat_k<false><<<mtP + mtA, 512, 0, stream>>>(
                meanW, meanC, xp_cur, meanR, xa_cur, WT_l,
                biasP + l * 256, biasA + l * 256, xp_nxt, xa_nxt, mtP);
            unsigned short* t;
            t = xa_cur; xa_cur = xa_nxt; xa_nxt = t;
            t = xp_cur; xp_cur = xp_nxt; xp_nxt = t;
        } else {
            gemm_fat_k<true><<<mtP + mtA, 512, 0, stream>>>(
                meanW, meanC, xp_cur, meanR, xa_cur, WT_l,
                biasP + l * 256, biasA + l * 256, outP, outA, mtP);
        }
    }
}

// Round 8
// 906.015 us; speedup vs baseline: 1.5483x; 1.0670x over previous
//
#include <hip/hip_runtime.h>
#include <hip/hip_bf16.h>
#include <cstdint>
#include <cstddef>

#define NA 50000
#define NP 100000
#define HH 256
#define LL 3
#define GP8 12500           // NP/8 agg blocks (8 nodes per 256-thread block)
#define GA8 6250            // NA/8 agg blocks

typedef __attribute__((ext_vector_type(8))) short short8;
typedef __attribute__((ext_vector_type(4))) float f32x4;

__device__ __forceinline__ float bf2f(unsigned int u16) {
    unsigned int x = u16 << 16;
    return __builtin_bit_cast(float, x);
}
__device__ __forceinline__ unsigned short f2bf(float f) {
    __hip_bfloat16 h = __float2bfloat16(f);
    return __builtin_bit_cast(unsigned short, h);
}

// ---------------- weight prep: WT[w][n*256+k] bf16, w = l*5 + t ----------------
// t0=Wl[l,0] (writes), t1=Wl[l,2] (cites), t2=Wr[l,0]+Wr[l,2] (P-root),
// t3=Wl[l,1] (rev), t4=Wr[l,1] (A-root)
__global__ void prep_w_k(const float* __restrict__ Wl, const float* __restrict__ Wr,
                         unsigned short* __restrict__ WT) {
    int gid = blockIdx.x * 256 + threadIdx.x;           // 15*65536 threads
    int w = gid >> 16;
    int within = gid & 65535;
    int n = within >> 8, k = within & 255;
    int l = w / 5, t = w % 5;
    float v;
    if (t == 0)      v = Wl[(size_t)((l * 3 + 0) * 256 + k) * 256 + n];
    else if (t == 1) v = Wl[(size_t)((l * 3 + 2) * 256 + k) * 256 + n];
    else if (t == 2) v = Wr[(size_t)((l * 3 + 0) * 256 + k) * 256 + n] +
                         Wr[(size_t)((l * 3 + 2) * 256 + k) * 256 + n];
    else if (t == 3) v = Wl[(size_t)((l * 3 + 1) * 256 + k) * 256 + n];
    else             v = Wr[(size_t)((l * 3 + 1) * 256 + k) * 256 + n];
    WT[(size_t)w * 65536 + n * 256 + k] = f2bf(v);
}

__global__ void prep_bias_k(const float* __restrict__ bl,
                            float* __restrict__ biasP, float* __restrict__ biasA) {
    int gid = blockIdx.x * 256 + threadIdx.x;           // 3*256 threads
    int l = gid >> 8, n = gid & 255;
    biasP[l * 256 + n] = bl[(l * 3 + 0) * 256 + n] + bl[(l * 3 + 2) * 256 + n];
    biasA[l * 256 + n] = bl[(l * 3 + 1) * 256 + n];
}

// ---------------- CSR build (fused over the 3 edge types) ----------------
__global__ void count3_k(const int* __restrict__ dw, const int* __restrict__ dc,
                         const int* __restrict__ dr, int* __restrict__ cnt,
                         int E, int egrid) {
    int b = blockIdx.x;
    int type = b / egrid, lb = b - type * egrid;
    int e = lb * 256 + threadIdx.x;
    if (e >= E) return;
    const int* d = (type == 0) ? dw : (type == 1) ? dc : dr;
    int base = (type == 0) ? 0 : (type == 1) ? NP : 2 * NP;
    atomicAdd(&cnt[base + d[e]], 1);
}

__global__ void scanA_k(const int* __restrict__ cnt, int* __restrict__ part,
                        int nbP, int nbA) {
    int b = blockIdx.x;
    int type, lb;
    if (b < nbP) { type = 0; lb = b; }
    else if (b < 2 * nbP) { type = 1; lb = b - nbP; }
    else { type = 2; lb = b - 2 * nbP; }
    int n = (type < 2) ? NP : NA;
    int base = (type == 0) ? 0 : (type == 1) ? NP : 2 * NP;
    __shared__ int sh[256];
    int i = lb * 256 + threadIdx.x;
    sh[threadIdx.x] = (i < n) ? cnt[base + i] : 0;
    __syncthreads();
    for (int s = 128; s > 0; s >>= 1) {
        if (threadIdx.x < s) sh[threadIdx.x] += sh[threadIdx.x + s];
        __syncthreads();
    }
    if (threadIdx.x == 0) part[type * 512 + lb] = sh[0];
}
__global__ void scanB_k(int* __restrict__ part, int nbP, int nbA) {
    int type = blockIdx.x;
    int nb = (type < 2) ? nbP : nbA;
    int* seg = part + type * 512;
    __shared__ int sh[512];
    int t = threadIdx.x;
    int v0 = (t < nb) ? seg[t] : 0;
    sh[t] = v0;
    __syncthreads();
    for (int off = 1; off < 512; off <<= 1) {
        int x = (t >= off) ? sh[t - off] : 0;
        __syncthreads();
        sh[t] += x;
        __syncthreads();
    }
    if (t < nb) seg[t] = sh[t] - v0;                    // exclusive
}
__global__ void scanC_k(const int* __restrict__ cnt, const int* __restrict__ part,
                        int* __restrict__ rp_w, int* __restrict__ rp_c,
                        int* __restrict__ rp_r, int nbP, int nbA) {
    int b = blockIdx.x;
    int type, lb;
    if (b < nbP) { type = 0; lb = b; }
    else if (b < 2 * nbP) { type = 1; lb = b - nbP; }
    else { type = 2; lb = b - 2 * nbP; }
    int n = (type < 2) ? NP : NA;
    int base = (type == 0) ? 0 : (type == 1) ? NP : 2 * NP;
    int* rowptr = (type == 0) ? rp_w : (type == 1) ? rp_c : rp_r;
    __shared__ int sh[256];
    int t = threadIdx.x;
    int i = lb * 256 + t;
    int v = (i < n) ? cnt[base + i] : 0;
    sh[t] = v;
    __syncthreads();
    for (int off = 1; off < 256; off <<= 1) {
        int x = (t >= off) ? sh[t - off] : 0;
        __syncthreads();
        if (t >= off) sh[t] += x;
        __syncthreads();
    }
    if (i < n) {
        int incl = sh[t];
        int pb = part[type * 512 + lb];
        rowptr[i] = pb + incl - v;
        if (i == n - 1) rowptr[n] = pb + incl;
    }
}
__global__ void fill3_k(const int* __restrict__ e_w, const int* __restrict__ e_c,
                        const int* __restrict__ e_r,
                        const int* __restrict__ rp_w, const int* __restrict__ rp_c,
                        const int* __restrict__ rp_r,
                        int* __restrict__ cursor,
                        int* __restrict__ col_w, int* __restrict__ col_c,
                        int* __restrict__ col_r, int E, int egrid) {
    int b = blockIdx.x;
    int type = b / egrid, lb = b - type * egrid;
    int e = lb * 256 + threadIdx.x;
    if (e >= E) return;
    const int* ep = (type == 0) ? e_w : (type == 1) ? e_c : e_r;
    const int* rowptr = (type == 0) ? rp_w : (type == 1) ? rp_c : rp_r;
    int* col = (type == 0) ? col_w : (type == 1) ? col_c : col_r;
    int base = (type == 0) ? 0 : (type == 1) ? NP : 2 * NP;
    int s = ep[e], d = ep[E + e];
    int pos = atomicAdd(&cursor[base + d], 1);
    col[rowptr[d] + pos] = s;
}

// ---------------- f32 -> bf16 cast (8 elems/thread) ----------------
__global__ void cast_bf16_k(const float* __restrict__ x, unsigned short* __restrict__ o, int n8) {
    int g = blockIdx.x * 256 + threadIdx.x;
    if (g >= n8) return;
    const float4* xp = reinterpret_cast<const float4*>(x) + (size_t)g * 2;
    float4 a = xp[0], b = xp[1];
    union { unsigned short u[8]; uint4 v; } r;
    r.u[0] = f2bf(a.x); r.u[1] = f2bf(a.y); r.u[2] = f2bf(a.z); r.u[3] = f2bf(a.w);
    r.u[4] = f2bf(b.x); r.u[5] = f2bf(b.y); r.u[6] = f2bf(b.z); r.u[7] = f2bf(b.w);
    reinterpret_cast<uint4*>(o)[g] = r.v;
}

// ---------------- fused CSR gather-mean v2: node per 32-lane half ----------------
// 256-thread block = 8 nodes. Lane i preloads col[beg+i]; neighbors broadcast via
// shfl(width=32) so gathers issue back-to-back (no col->gather serial chain).
__global__ void agg_fused_k(const unsigned short* __restrict__ xa,
                            const unsigned short* __restrict__ xp,
                            const int* __restrict__ rp_w, const int* __restrict__ col_w,
                            const int* __restrict__ rp_c, const int* __restrict__ col_c,
                            const int* __restrict__ rp_r, const int* __restrict__ col_r,
                            unsigned short* __restrict__ mW,
                            unsigned short* __restrict__ mC,
                            unsigned short* __restrict__ mR) {
    int b = blockIdx.x;
    const unsigned short* x; const int* rp; const int* cl; unsigned short* mn; int nd;
    if (b < GP8)            { x = xa; rp = rp_w; cl = col_w; mn = mW; nd = NP; }
    else if (b < 2 * GP8)   { b -= GP8; x = xp; rp = rp_c; cl = col_c; mn = mC; nd = NP; }
    else                    { b -= 2 * GP8; x = xp; rp = rp_r; cl = col_r; mn = mR; nd = NA; }
    int node = b * 8 + (threadIdx.x >> 5);
    if (node >= nd) return;
    const int l32 = threadIdx.x & 31;
    int beg = rp[node], end = rp[node + 1];
    int deg = end - beg;
    float a0 = 0.f, a1 = 0.f, a2 = 0.f, a3 = 0.f, a4 = 0.f, a5 = 0.f, a6 = 0.f, a7 = 0.f;
    for (int base = 0; base < deg; base += 32) {
        int n = min(deg - base, 32);
        int myc = (base + l32 < deg) ? cl[beg + base + l32] : 0;
        int i = 0;
        for (; i + 1 < n; i += 2) {
            int s0 = __shfl(myc, i, 32);
            int s1 = __shfl(myc, i + 1, 32);
            uint4 v0 = *reinterpret_cast<const uint4*>(x + (size_t)s0 * 256 + l32 * 8);
            uint4 v1 = *reinterpret_cast<const uint4*>(x + (size_t)s1 * 256 + l32 * 8);
            a0 += bf2f(v0.x & 0xffffu); a1 += bf2f(v0.x >> 16);
            a2 += bf2f(v0.y & 0xffffu); a3 += bf2f(v0.y >> 16);
            a4 += bf2f(v0.z & 0xffffu); a5 += bf2f(v0.z >> 16);
            a6 += bf2f(v0.w & 0xffffu); a7 += bf2f(v0.w >> 16);
            a0 += bf2f(v1.x & 0xffffu); a1 += bf2f(v1.x >> 16);
            a2 += bf2f(v1.y & 0xffffu); a3 += bf2f(v1.y >> 16);
            a4 += bf2f(v1.z & 0xffffu); a5 += bf2f(v1.z >> 16);
            a6 += bf2f(v1.w & 0xffffu); a7 += bf2f(v1.w >> 16);
        }
        if (i < n) {
            int s0 = __shfl(myc, i, 32);
            uint4 v0 = *reinterpret_cast<const uint4*>(x + (size_t)s0 * 256 + l32 * 8);
            a0 += bf2f(v0.x & 0xffffu); a1 += bf2f(v0.x >> 16);
            a2 += bf2f(v0.y & 0xffffu); a3 += bf2f(v0.y >> 16);
            a4 += bf2f(v0.z & 0xffffu); a5 += bf2f(v0.z >> 16);
            a6 += bf2f(v0.w & 0xffffu); a7 += bf2f(v0.w >> 16);
        }
    }
    float sc = (deg > 0) ? 1.0f / (float)deg : 0.f;
    uint4 r;
    r.x = (unsigned int)f2bf(a0 * sc) | ((unsigned int)f2bf(a1 * sc) << 16);
    r.y = (unsigned int)f2bf(a2 * sc) | ((unsigned int)f2bf(a3 * sc) << 16);
    r.z = (unsigned int)f2bf(a4 * sc) | ((unsigned int)f2bf(a5 * sc) << 16);
    r.w = (unsigned int)f2bf(a6 * sc) | ((unsigned int)f2bf(a7 * sc) << 16);
    *reinterpret_cast<uint4*>(mn + (size_t)node * 256 + l32 * 8) = r;
}

// ---------------- fat fused GEMM: 128 rows x full 256 cols, reg-capped at 128 ----------------
// B staged in two sequential 64KB halves; A fragments loaded once, reused for both halves.
// Epilogue staged through LDS -> full-line vector stores. __launch_bounds__(512,2):
// VGPR cap 128 (acc[2][8]=64 + a4[8]=32 + working fits; NO spill). LDS caps at 2 blocks/CU anyway.
#define EP_STRIDE 132        // f32 row stride in epilogue LDS tile
template <bool LAST>
__global__ __launch_bounds__(512, 2)
void gemm_fat_k(const unsigned short* __restrict__ mW, const unsigned short* __restrict__ mC,
                const unsigned short* __restrict__ xp, const unsigned short* __restrict__ mR,
                const unsigned short* __restrict__ xa, const unsigned short* __restrict__ WT_l,
                const float* __restrict__ biasP, const float* __restrict__ biasA,
                void* __restrict__ outP, void* __restrict__ outA, int mtP) {
    __shared__ char lds[128 * EP_STRIDE * 4];           // 67584 B >= 65536 B for B-staging
    char* bsh = lds;
    float* eps = reinterpret_cast<float*>(lds);
    const int tid = threadIdx.x;

    const bool isP = (int)blockIdx.x < mtP;
    const int tile = isP ? blockIdx.x : blockIdx.x - mtP;
    const int parts = isP ? 3 : 2;
    const unsigned short* A0 = isP ? mW : mR;
    const unsigned short* A1 = isP ? mC : xa;
    const unsigned short* A2 = xp;
    const unsigned short* WTj = isP ? WT_l : WT_l + 3 * 65536;
    const float* bias = isP ? biasP : biasA;
    void* out = isP ? outP : outA;
    const int M = isP ? NP : NA;

    const int wid = tid >> 6;
    const int l = tid & 63;
    const int kgrp = (l >> 4) << 3;                     // 0,8,16,24
    int row = tile * 128 + (wid << 4) + (l & 15);
    int rowc = row < M ? row : M - 1;

    f32x4 acc[2][8];
    #pragma unroll
    for (int h = 0; h < 2; ++h)
        #pragma unroll
        for (int t = 0; t < 8; ++t) acc[h][t] = f32x4{0.f, 0.f, 0.f, 0.f};

    bool first = true;
    for (int p = 0; p < parts; ++p) {
        const unsigned short* Ap = (p == 0) ? A0 : (p == 1) ? A1 : A2;
        // A fragments once per part, reused for both N-halves
        uint4 a4[8];
        const unsigned short* Arow = Ap + (size_t)rowc * 256 + kgrp;
        #pragma unroll
        for (int s = 0; s < 8; ++s)
            a4[s] = *reinterpret_cast<const uint4*>(Arow + s * 32);

        #pragma unroll
        for (int h = 0; h < 2; ++h) {
            if (!first) __syncthreads();                // prior LDS reads done
            first = false;
            const unsigned short* Wt = WTj + (size_t)p * 65536 + h * (128 * 256);
            #pragma unroll
            for (int i = 0; i < 8; ++i) {               // stage 128 n-rows x 256 k, swizzled
                int byte = (i * 512 + tid) * 16;
                uint4 v = *reinterpret_cast<const uint4*>((const char*)Wt + byte);
                *reinterpret_cast<uint4*>(bsh + (byte ^ (((byte >> 9) & 7) << 4))) = v;
            }
            __syncthreads();
            #pragma unroll
            for (int s = 0; s < 8; ++s) {
                short8 a = __builtin_bit_cast(short8, a4[s]);
                #pragma unroll
                for (int t = 0; t < 8; ++t) {
                    int nl = (t << 4) + (l & 15);
                    int byte = (nl * 512 + s * 64 + kgrp * 2) ^ ((nl & 7) << 4);
                    short8 bfr = __builtin_bit_cast(short8, *reinterpret_cast<const uint4*>(bsh + byte));
                    acc[h][t] = __builtin_amdgcn_mfma_f32_16x16x32_bf16(a, bfr, acc[h][t], 0, 0, 0);
                }
            }
        }
    }

    // ---- epilogue via LDS: coalesced full-line vector stores ----
    const int col = l & 15;
    const int rloc0 = (wid << 4) + ((l >> 4) << 2);     // local row base of this thread's quads
    #pragma unroll
    for (int h = 0; h < 2; ++h) {
        __syncthreads();                                // LDS (B or prev epilogue) reads done
        #pragma unroll
        for (int t = 0; t < 8; ++t) {
            int gc = (h << 7) + (t << 4) + col;
            float badd = bias[gc];
            #pragma unroll
            for (int j = 0; j < 4; ++j)
                eps[(rloc0 + j) * EP_STRIDE + (t << 4) + col] = acc[h][t][j] + badd;
        }
        __syncthreads();
        if (LAST) {
            // f32 out: 128 rows x 128 cols x 4B; 32 float4 chunks/row, 8 per thread
            float* fout = reinterpret_cast<float*>(out);
            #pragma unroll
            for (int i = 0; i < 8; ++i) {
                int c = i * 512 + tid;
                int r = c >> 5, within = c & 31;
                int rg = tile * 128 + r;
                if (rg < M) {
                    const float* src = eps + r * EP_STRIDE + within * 4;
                    float4 v = *reinterpret_cast<const float4*>(src);
                    *reinterpret_cast<float4*>(fout + (size_t)rg * 256 + (h << 7) + within * 4) = v;
                }
            }
        } else {
            // bf16 out: 16 uint4 chunks/row, 4 per thread
            unsigned short* bout = reinterpret_cast<unsigned short*>(out);
            #pragma unroll
            for (int i = 0; i < 4; ++i) {
                int c = i * 512 + tid;
                int r = c >> 4, within = c & 15;
                int rg = tile * 128 + r;
                if (rg < M) {
                    const float* src = eps + r * EP_STRIDE + within * 8;
                    float4 lo = *reinterpret_cast<const float4*>(src);
                    float4 hi = *reinterpret_cast<const float4*>(src + 4);
                    uint4 v;
                    v.x = (unsigned int)f2bf(lo.x) | ((unsigned int)f2bf(lo.y) << 16);
                    v.y = (unsigned int)f2bf(lo.z) | ((unsigned int)f2bf(lo.w) << 16);
                    v.z = (unsigned int)f2bf(hi.x) | ((unsigned int)f2bf(hi.y) << 16);
                    v.w = (unsigned int)f2bf(hi.z) | ((unsigned int)f2bf(hi.w) << 16);
                    *reinterpret_cast<uint4*>(bout + (size_t)rg * 256 + (h << 7) + within * 8) = v;
                }
            }
        }
    }
}

extern "C" void kernel_launch(void* const* d_in, const int* in_sizes, int n_in,
                              void* d_out, int out_size, void* d_ws, size_t ws_size,
                              hipStream_t stream) {
    const float* x_author = (const float*)d_in[0];
    const float* x_paper  = (const float*)d_in[1];
    const int* e_w = (const int*)d_in[2];
    const int* e_r = (const int*)d_in[3];
    const int* e_c = (const int*)d_in[4];
    const float* Wl = (const float*)d_in[5];
    const float* bl = (const float*)d_in[6];
    const float* Wr = (const float*)d_in[7];
    const int E = in_sizes[2] / 2;

    float* outA = (float*)d_out;                         // [NA,256] f32
    float* outP = (float*)d_out + (size_t)NA * HH;       // [NP,256] f32

    size_t off = 0;
    auto carve = [&](size_t bytes) {
        void* p = (char*)d_ws + off;
        off += (bytes + 255) & ~(size_t)255;
        return p;
    };
    unsigned short* xa0   = (unsigned short*)carve((size_t)NA * HH * 2);
    unsigned short* xp0   = (unsigned short*)carve((size_t)NP * HH * 2);
    unsigned short* meanW = (unsigned short*)carve((size_t)NP * HH * 2);
    unsigned short* meanC = (unsigned short*)carve((size_t)NP * HH * 2);
    unsigned short* meanR = (unsigned short*)carve((size_t)NA * HH * 2);
    unsigned short* WT    = (unsigned short*)carve((size_t)15 * 65536 * 2);
    float* biasP = (float*)carve((size_t)LL * HH * 4);
    float* biasA = (float*)carve((size_t)LL * HH * 4);
    int* cnt    = (int*)carve((size_t)(2 * NP + NA) * 4);   // degree counts, reused as fill cursor
    int* rp_w   = (int*)carve((size_t)(NP + 1) * 4);
    int* rp_c   = (int*)carve((size_t)(NP + 1) * 4);
    int* rp_r   = (int*)carve((size_t)(NA + 1) * 4);
    int* part   = (int*)carve((size_t)2048 * 4);
    int* col_w  = (int*)carve((size_t)E * 4);
    int* col_c  = (int*)carve((size_t)E * 4);
    int* col_r  = (int*)carve((size_t)E * 4);
    (void)off; (void)ws_size; (void)n_in; (void)out_size;

    const size_t cntBytes = (size_t)(2 * NP + NA) * 4;
    const int egrid = (E + 255) / 256;
    const int nbP = (NP + 255) / 256, nbA = (NA + 255) / 256;
    const int mtP = (NP + 127) / 128, mtA = (NA + 127) / 128;

    // ---- one-time: weights, biases, CSR ----
    hipMemsetAsync(cnt, 0, cntBytes, stream);
    prep_w_k<<<3840, 256, 0, stream>>>(Wl, Wr, WT);
    prep_bias_k<<<3, 256, 0, stream>>>(bl, biasP, biasA);
    count3_k<<<3 * egrid, 256, 0, stream>>>(e_w + E, e_c + E, e_r + E, cnt, E, egrid);
    scanA_k<<<2 * nbP + nbA, 256, 0, stream>>>(cnt, part, nbP, nbA);
    scanB_k<<<3, 512, 0, stream>>>(part, nbP, nbA);
    scanC_k<<<2 * nbP + nbA, 256, 0, stream>>>(cnt, part, rp_w, rp_c, rp_r, nbP, nbA);
    hipMemsetAsync(cnt, 0, cntBytes, stream);            // re-zero -> fill cursor
    fill3_k<<<3 * egrid, 256, 0, stream>>>(e_w, e_c, e_r, rp_w, rp_c, rp_r,
                                           cnt, col_w, col_c, col_r, E, egrid);

    cast_bf16_k<<<(NA * HH / 8 + 255) / 256, 256, 0, stream>>>(x_author, xa0, NA * HH / 8);
    cast_bf16_k<<<(NP * HH / 8 + 255) / 256, 256, 0, stream>>>(x_paper, xp0, NP * HH / 8);

    // bf16 ping set inside d_out (overwritten by f32 at l=2)
    unsigned short* xa1 = (unsigned short*)d_out;
    unsigned short* xp1 = xa1 + (size_t)NA * HH;

    unsigned short* xa_cur = xa0; unsigned short* xp_cur = xp0;
    unsigned short* xa_nxt = xa1; unsigned short* xp_nxt = xp1;

    const int aggGrid = 2 * GP8 + GA8;

    for (int l = 0; l < LL; ++l) {
        const unsigned short* WT_l = WT + (size_t)l * 5 * 65536;
        agg_fused_k<<<aggGrid, 256, 0, stream>>>(xa_cur, xp_cur, rp_w, col_w,
                                                 rp_c, col_c, rp_r, col_r,
                                                 meanW, meanC, meanR);
        if (l < LL - 1) {
            gemm_fat_k<false><<<mtP + mtA, 512, 0, stream>>>(
                meanW, meanC, xp_cur, meanR, xa_cur, WT_l,
                biasP + l * 256, biasA + l * 256, xp_nxt, xa_nxt, mtP);
            unsigned short* t;
            t = xa_cur; xa_cur = xa_nxt; xa_nxt = t;
            t = xp_cur; xp_cur = xp_nxt; xp_nxt = t;
        } else {
            gemm_fat_k<true><<<mtP + mtA, 512, 0, stream>>>(
                meanW, meanC, xp_cur, meanR, xa_cur, WT_l,
                biasP + l * 256, biasA + l * 256, outP, outA, mtP);
        }
    }
}